// Round 1
// baseline (401.648 us; speedup 1.0000x reference)
//
#include <hip/hip_runtime.h>

// MHA decode: B=256, NKEYS=2048, EMB=512, H=8, dh=64, f32.
// Memory-bound: must stream key+value (2.148 GB) once -> ~341us floor @6.3TB/s.

#define NB    256
#define NK    2048
#define EMBD  512
#define NH    8
#define DH    64

// One block per (b,h). 256 threads = 4 waves. Each wave splits into 4 groups
// of 16 lanes; a group handles one key per iteration with float4 loads
// (16 lanes x 16B = 256B contiguous -> coalesced).
__global__ __launch_bounds__(256) void attn_kernel(
    const float* __restrict__ q,
    const float* __restrict__ kptr,
    const float* __restrict__ vptr,
    const int* __restrict__ mask,
    float* __restrict__ merged)
{
    const int bh   = blockIdx.x;
    const int b    = bh >> 3;
    const int h    = bh & 7;
    const int t    = threadIdx.x;
    const int lane = t & 63;
    const int w    = t >> 6;       // wave 0..3
    const int grp  = lane >> 4;    // group 0..3 within wave
    const int li   = lane & 15;    // lane within group

    __shared__ float sc[NK];       // scores -> exp(p) (8KB)
    __shared__ float red[8];
    __shared__ float ored[4 * DH];
    __shared__ float s_max, s_denom;

    // q fragment for this lane's dim chunk (dims li*4 .. li*4+3 of this head)
    const float4 q4 = *reinterpret_cast<const float4*>(
        q + (size_t)b * EMBD + h * DH + li * 4);

    const float* kbase = kptr + (size_t)b * NK * EMBD + h * DH;
    const float* vbase = vptr + (size_t)b * NK * EMBD + h * DH;

    // ---- score pass: 16 keys per block-iteration ----
    for (int it = 0; it < NK / 16; ++it) {
        const int key = it * 16 + w * 4 + grp;
        const float4 k4 = *reinterpret_cast<const float4*>(
            kbase + (size_t)key * EMBD + li * 4);
        float s = q4.x * k4.x + q4.y * k4.y + q4.z * k4.z + q4.w * k4.w;
        s += __shfl_xor(s, 8, 16);
        s += __shfl_xor(s, 4, 16);
        s += __shfl_xor(s, 2, 16);
        s += __shfl_xor(s, 1, 16);
        if (li == 0) sc[key] = s * 0.125f;   // 1/sqrt(64)
    }
    __syncthreads();

    // ---- block max over all 2048 raw scores (>= masked max, numerically safe) ----
    float lmax = -INFINITY;
    #pragma unroll
    for (int i = 0; i < 8; ++i) lmax = fmaxf(lmax, sc[t + 256 * i]);
    for (int off = 32; off >= 1; off >>= 1)
        lmax = fmaxf(lmax, __shfl_xor(lmax, off, 64));
    if (lane == 0) red[w] = lmax;
    __syncthreads();
    if (t == 0) s_max = fmaxf(fmaxf(red[0], red[1]), fmaxf(red[2], red[3]));
    __syncthreads();
    const float m = s_max;

    // ---- exp + mask (mask==1 -> masked out) + denom ----
    const int* mrow = mask + (size_t)b * NK;
    float lsum = 0.f;
    #pragma unroll
    for (int i = 0; i < 8; ++i) {
        const int kk = t + 256 * i;
        const int mk = mrow[kk];
        const float p = mk ? 0.f : __expf(sc[kk] - m);
        sc[kk] = p;
        lsum += p;
    }
    for (int off = 32; off >= 1; off >>= 1) lsum += __shfl_xor(lsum, off, 64);
    if (lane == 0) red[w] = lsum;
    __syncthreads();
    if (t == 0) s_denom = red[0] + red[1] + red[2] + red[3];
    __syncthreads();

    // ---- V accumulation, same group layout ----
    float4 acc = {0.f, 0.f, 0.f, 0.f};
    for (int it = 0; it < NK / 16; ++it) {
        const int key = it * 16 + w * 4 + grp;
        const float4 v4 = *reinterpret_cast<const float4*>(
            vbase + (size_t)key * EMBD + li * 4);
        const float p = sc[key];   // broadcast within group
        acc.x += p * v4.x; acc.y += p * v4.y;
        acc.z += p * v4.z; acc.w += p * v4.w;
    }
    // reduce the 4 groups of each wave (xor 16, 32)
    #pragma unroll
    for (int off = 16; off <= 32; off <<= 1) {
        acc.x += __shfl_xor(acc.x, off, 64);
        acc.y += __shfl_xor(acc.y, off, 64);
        acc.z += __shfl_xor(acc.z, off, 64);
        acc.w += __shfl_xor(acc.w, off, 64);
    }
    if (lane < 16) {
        ored[w * DH + li * 4 + 0] = acc.x;
        ored[w * DH + li * 4 + 1] = acc.y;
        ored[w * DH + li * 4 + 2] = acc.z;
        ored[w * DH + li * 4 + 3] = acc.w;
    }
    __syncthreads();
    if (t < DH) {
        float o = ored[t] + ored[DH + t] + ored[2 * DH + t] + ored[3 * DH + t];
        o /= s_denom;
        merged[(size_t)b * EMBD + h * DH + t] = o;
    }
}

// out[b,j] = sum_i merged[b,i] * Wo[j,i].  Wo is 1MB -> L2 resident.
// Safe when merged aliases out: row b staged to LDS + barrier before writes.
__global__ __launch_bounds__(256) void proj_kernel(
    const float* __restrict__ merged,
    const float* __restrict__ Wo,
    float* __restrict__ out)
{
    const int b = blockIdx.x;
    const int t = threadIdx.x;
    __shared__ float mrow[EMBD];
    *reinterpret_cast<float2*>(&mrow[t * 2]) =
        *reinterpret_cast<const float2*>(&merged[(size_t)b * EMBD + t * 2]);
    __syncthreads();

    const float4* mv = reinterpret_cast<const float4*>(mrow);
    #pragma unroll
    for (int half = 0; half < 2; ++half) {
        const int j = t + half * 256;
        const float4* wrow = reinterpret_cast<const float4*>(Wo + (size_t)j * EMBD);
        float s = 0.f;
        #pragma unroll 4
        for (int i = 0; i < EMBD / 4; ++i) {
            const float4 wv = wrow[i];
            const float4 qv = mv[i];
            s += wv.x * qv.x + wv.y * qv.y + wv.z * qv.z + wv.w * qv.w;
        }
        out[(size_t)b * EMBD + j] = s;
    }
}

extern "C" void kernel_launch(void* const* d_in, const int* in_sizes, int n_in,
                              void* d_out, int out_size, void* d_ws, size_t ws_size,
                              hipStream_t stream) {
    const float* q    = (const float*)d_in[0];
    const float* kptr = (const float*)d_in[1];
    const float* vptr = (const float*)d_in[2];
    const float* Wo   = (const float*)d_in[3];
    const int*   mask = (const int*)d_in[4];
    float* out = (float*)d_out;

    // merged is 512KB; use workspace if available, else write into d_out
    // (proj_kernel is in-place safe per block).
    float* merged = (ws_size >= (size_t)NB * EMBD * sizeof(float))
                        ? (float*)d_ws : out;

    attn_kernel<<<NB * NH, 256, 0, stream>>>(q, kptr, vptr, mask, merged);
    proj_kernel<<<NB, 256, 0, stream>>>(merged, Wo, out);
}